// Round 5
// baseline (112.899 us; speedup 1.0000x reference)
//
#include <hip/hip_runtime.h>
#include <hip/hip_bf16.h>
#include <math.h>

#define D_MODEL 1024
#define TLEN    2048

typedef __attribute__((ext_vector_type(8))) short short8;
typedef __attribute__((ext_vector_type(4))) float f32x4;

static __device__ __forceinline__ unsigned short f2bf(float f) {
    __hip_bfloat16 h = __float2bfloat16(f);
    return __builtin_bit_cast(unsigned short, h);
}

static __device__ __forceinline__ void lds_cp16(void* lds, const void* g) {
    __builtin_amdgcn_global_load_lds(
        (const __attribute__((address_space(1))) unsigned int*)g,
        (__attribute__((address_space(3))) unsigned int*)lds, 16, 0, 0);
}

// ---------------------------------------------------------------------------
// Kernel 0: pack W fp32 [384][1024] -> wt bf16 [np3][kt16][h128][k64],
// swizzled (8-short k-group XOR h&7) for linear gload_lds + swizzled ds_read.
// ---------------------------------------------------------------------------
__global__ __launch_bounds__(256) void pack_w(const float* __restrict__ W,
                                              unsigned short* __restrict__ wt) {
    const int id = blockIdx.x * 256 + threadIdx.x;   // 49152 threads
    const int h  = id >> 7;
    const int kg = id & 127;
    const int k0 = kg * 8;
    const int kt = k0 >> 6;
    const int kin = k0 & 63;
    const int np = h >> 7;
    const int hp = h & 127;
    const float4 a = *(const float4*)&W[(size_t)h * D_MODEL + k0];
    const float4 b = *(const float4*)&W[(size_t)h * D_MODEL + k0 + 4];
    short8 v;
    v[0] = (short)f2bf(a.x); v[1] = (short)f2bf(a.y);
    v[2] = (short)f2bf(a.z); v[3] = (short)f2bf(a.w);
    v[4] = (short)f2bf(b.x); v[5] = (short)f2bf(b.y);
    v[6] = (short)f2bf(b.z); v[7] = (short)f2bf(b.w);
    const size_t dst = ((size_t)(np * 16 + kt) * 128 + hp) * 64 + (kin ^ ((hp & 7) * 8));
    *(short8*)&wt[dst] = v;
}

// ---------------------------------------------------------------------------
// Kernel 1: qkv = x @ W^T, bf16 MFMA. BM=64, BN=128, BK=64. Grid (256,3).
// Q panel (np==0) pre-scaled by 1/sqrt(128) so attn skips the scale mul.
// ---------------------------------------------------------------------------
__global__ __launch_bounds__(256, 4) void qkv_gemm(const float* __restrict__ x,
                                                   const unsigned short* __restrict__ wt,
                                                   unsigned short* __restrict__ qk,
                                                   unsigned short* __restrict__ vt) {
    __shared__ unsigned short As[64][88];
    __shared__ unsigned short Bs[128 * 64];

    const int tid  = threadIdx.x;
    const int lane = tid & 63;
    const int w    = tid >> 6;
    const int wm   = w >> 1, wn = w & 1;
    const int cc   = lane & 15, g = lane >> 4;
    const int row0 = blockIdx.x * 64;
    const int np   = blockIdx.y;

    const int xr  = tid >> 2;
    const int xc0 = (tid & 3) * 16;

    const f32x4 zero = {0.f, 0.f, 0.f, 0.f};
    f32x4 acc[2][4];
#pragma unroll
    for (int i = 0; i < 2; ++i)
#pragma unroll
        for (int j = 0; j < 4; ++j) acc[i][j] = zero;

    const float* xrow = x + (size_t)(row0 + xr) * D_MODEL + xc0;
    float4 xa[4];
#pragma unroll
    for (int i = 0; i < 4; ++i) xa[i] = *(const float4*)(xrow + i * 4);

    const unsigned short* wtile0 =
        wt + (size_t)np * 16 * 128 * 64 + (w * 4 * 1024 + lane * 16) / 2;
    unsigned short* bdst = Bs + (w * 4 * 1024) / 2;

    for (int kt = 0; kt < 16; ++kt) {
        __syncthreads();
        {
            short8 s0, s1;
            s0[0] = (short)f2bf(xa[0].x); s0[1] = (short)f2bf(xa[0].y);
            s0[2] = (short)f2bf(xa[0].z); s0[3] = (short)f2bf(xa[0].w);
            s0[4] = (short)f2bf(xa[1].x); s0[5] = (short)f2bf(xa[1].y);
            s0[6] = (short)f2bf(xa[1].z); s0[7] = (short)f2bf(xa[1].w);
            s1[0] = (short)f2bf(xa[2].x); s1[1] = (short)f2bf(xa[2].y);
            s1[2] = (short)f2bf(xa[2].z); s1[3] = (short)f2bf(xa[2].w);
            s1[4] = (short)f2bf(xa[3].x); s1[5] = (short)f2bf(xa[3].y);
            s1[6] = (short)f2bf(xa[3].z); s1[7] = (short)f2bf(xa[3].w);
            *(short8*)&As[xr][xc0]     = s0;
            *(short8*)&As[xr][xc0 + 8] = s1;
        }
        const unsigned short* wtk = wtile0 + (size_t)kt * 128 * 64;
#pragma unroll
        for (int i = 0; i < 4; ++i)
            lds_cp16(bdst + i * 512, wtk + i * 512);
        __syncthreads();

        short8 af[2][2], bf[2][4];
#pragma unroll
        for (int ks = 0; ks < 2; ++ks) {
#pragma unroll
            for (int mt = 0; mt < 2; ++mt)
                af[ks][mt] = *(const short8*)&As[wm * 32 + mt * 16 + cc][ks * 32 + g * 8];
#pragma unroll
            for (int nt = 0; nt < 4; ++nt) {
                const int h = wn * 64 + nt * 16 + cc;
                bf[ks][nt] = *(const short8*)&Bs[h * 64 + (((ks * 4 + g) ^ (h & 7)) << 3)];
            }
        }
        if (kt + 1 < 16) {
#pragma unroll
            for (int i = 0; i < 4; ++i)
                xa[i] = *(const float4*)(xrow + (kt + 1) * 64 + i * 4);
        }
#pragma unroll
        for (int ks = 0; ks < 2; ++ks)
#pragma unroll
            for (int mt = 0; mt < 2; ++mt)
#pragma unroll
                for (int nt = 0; nt < 4; ++nt)
                    acc[mt][nt] = __builtin_amdgcn_mfma_f32_16x16x32_bf16(
                        af[ks][mt], bf[ks][nt], acc[mt][nt], 0, 0, 0);
    }

    const int bb  = row0 >> 11;
    const int tr0 = row0 & 2047;
    const float qs = (np == 0) ? 0.08838834764831845f : 1.0f;  // fold 1/sqrt(128) into Q
#pragma unroll
    for (int mt = 0; mt < 2; ++mt)
#pragma unroll
        for (int nt = 0; nt < 4; ++nt) {
            const int colp = wn * 64 + nt * 16;
            if (np < 2) {
#pragma unroll
                for (int r = 0; r < 4; ++r) {
                    const int row = row0 + wm * 32 + mt * 16 + g * 4 + r;
                    qk[(size_t)row * 256 + np * 128 + colp + cc] = f2bf(acc[mt][nt][r] * qs);
                }
            } else {
                const int d    = colp + cc;
                const int trow = tr0 + wm * 32 + mt * 16 + g * 4;
                ushort4 u;
                u.x = f2bf(acc[mt][nt][0]);
                u.y = f2bf(acc[mt][nt][1]);
                u.z = f2bf(acc[mt][nt][2]);
                u.w = f2bf(acc[mt][nt][3]);
                *(ushort4*)&vt[((size_t)(bb * 128 + d)) * TLEN + trow] = u;
            }
        }
}

// ---------------------------------------------------------------------------
// Kernel 2: causal flash attention. QBLK=32, grid (64,8)=512 blocks,
// 256 thr = 4 waves: wq=w&1 (16-row q subtile), gg=w>>1 (even/odd KV tiles).
// LDS 81.1 KB -> 2 blocks/CU. Defer-max rescale (THR=8). Q pre-scaled.
// Merge buffer overlaid on Ks (dead after last QK^T).
// ---------------------------------------------------------------------------
__global__ __launch_bounds__(256, 2) void attn_fwd(const unsigned short* __restrict__ qk,
                                                   const unsigned short* __restrict__ vt,
                                                   float* __restrict__ out) {
    __shared__ unsigned short Ks[2][64][136];   // 34816 B (also merge Co overlay)
    __shared__ unsigned short Vs[2][128][72];   // 36864 B
    __shared__ unsigned short Ps[4][16][72];    //  9216 B
    __shared__ float Cml[2][16][2];             //   256 B   => 81152 B total

    const int tid  = threadIdx.x;
    const int lane = tid & 63;
    const int w    = tid >> 6;       // 0..3
    const int gg   = w >> 1;         // KV parity group
    const int wq   = w & 1;          // q sub-tile
    const int cc   = lane & 15, g = lane >> 4;
    const int qt   = 63 - (int)blockIdx.x;   // long blocks first
    const int b    = blockIdx.y;
    const int q0   = qt * 32;

    const int gl   = tid & 127;      // within-group stage id
    const int kRow = gl >> 1;        // 0..63
    const int kC   = (gl & 1) * 64;  // 0,64

    // Q A-fragments (pre-scaled in gemm), kernel lifetime
    short8 qf[4];
    {
        const unsigned short* qb =
            qk + ((size_t)(b * TLEN + q0 + wq * 16 + cc)) * 256 + g * 8;
#pragma unroll
        for (int kt = 0; kt < 4; ++kt) qf[kt] = *(const short8*)(qb + kt * 32);
    }

    const f32x4 zero = {0.f, 0.f, 0.f, 0.f};
    f32x4 o[8];
#pragma unroll
    for (int nt = 0; nt < 8; ++nt) o[nt] = zero;
    float m[4] = {-INFINITY, -INFINITY, -INFINITY, -INFINITY};
    float l[4] = {0.f, 0.f, 0.f, 0.f};

    const int n      = (q0 + 31) / 64 + 1;   // KV tiles
    const int nsteps = (n + 1) >> 1;

    short8 kr[8], vr[8];
    const unsigned short* kbase = qk + ((size_t)(b * TLEN + kRow)) * 256 + 128 + kC;
    const unsigned short* vbase = vt + ((size_t)(b * 128 + gl)) * TLEN;

    {
        const int t0 = (gg < n) ? gg : (n - 1);
#pragma unroll
        for (int i = 0; i < 8; ++i) kr[i] = *(const short8*)(kbase + (size_t)t0 * 64 * 256 + i * 8);
#pragma unroll
        for (int i = 0; i < 8; ++i) vr[i] = *(const short8*)(vbase + t0 * 64 + i * 8);
    }

    for (int s = 0; s < nsteps; ++s) {
        const int  t      = 2 * s + gg;
        const bool active = (t < n);
        __syncthreads();
#pragma unroll
        for (int i = 0; i < 8; ++i) *(short8*)&Ks[gg][kRow][kC + i * 8] = kr[i];
#pragma unroll
        for (int i = 0; i < 8; ++i) *(short8*)&Vs[gg][gl][i * 8] = vr[i];
        __syncthreads();
        if (s + 1 < nsteps) {
            int tn = 2 * (s + 1) + gg;
            if (tn > n - 1) tn = n - 1;
#pragma unroll
            for (int i = 0; i < 8; ++i) kr[i] = *(const short8*)(kbase + (size_t)tn * 64 * 256 + i * 8);
#pragma unroll
            for (int i = 0; i < 8; ++i) vr[i] = *(const short8*)(vbase + tn * 64 + i * 8);
        }
        if (active) {
            const int j0 = t * 64;
            // S = Q K^T (Q pre-scaled)
            f32x4 sreg[4];
#pragma unroll
            for (int jt = 0; jt < 4; ++jt) sreg[jt] = zero;
#pragma unroll
            for (int kt = 0; kt < 4; ++kt)
#pragma unroll
                for (int jt = 0; jt < 4; ++jt) {
                    const short8 kf = *(const short8*)&Ks[gg][jt * 16 + cc][kt * 32 + g * 8];
                    sreg[jt] = __builtin_amdgcn_mfma_f32_16x16x32_bf16(qf[kt], kf, sreg[jt], 0, 0, 0);
                }

            const bool diag = (t == n - 1) && (j0 + 63 > q0);   // tile may cross diagonal
            float sv[4][4], tmr[4];
#pragma unroll
            for (int reg = 0; reg < 4; ++reg) {
                const int qrow = q0 + wq * 16 + g * 4 + reg;
                float vmax = -INFINITY;
#pragma unroll
                for (int jt = 0; jt < 4; ++jt) {
                    float v = sreg[jt][reg];
                    if (diag && (j0 + jt * 16 + cc) > qrow) v = -INFINITY;
                    sv[reg][jt] = v;
                    vmax = fmaxf(vmax, v);
                }
#pragma unroll
                for (int off = 8; off >= 1; off >>= 1)
                    vmax = fmaxf(vmax, __shfl_xor(vmax, off, 16));
                tmr[reg] = vmax;
            }
            // defer-max: skip rescale when all rows grew by <= 8
            const bool small = (tmr[0] <= m[0] + 8.f) && (tmr[1] <= m[1] + 8.f) &&
                               (tmr[2] <= m[2] + 8.f) && (tmr[3] <= m[3] + 8.f);
            if (!__all(small)) {
#pragma unroll
                for (int reg = 0; reg < 4; ++reg) {
                    const float newm  = fmaxf(m[reg], tmr[reg]);
                    const float alpha = __expf(m[reg] - newm);
                    m[reg] = newm;
                    l[reg] *= alpha;
#pragma unroll
                    for (int nt = 0; nt < 8; ++nt) o[nt][reg] *= alpha;
                }
            }
#pragma unroll
            for (int reg = 0; reg < 4; ++reg) {
                float rs = 0.f;
#pragma unroll
                for (int jt = 0; jt < 4; ++jt) {
                    const float p = __expf(sv[reg][jt] - m[reg]);
                    rs += p;
                    Ps[w][g * 4 + reg][jt * 16 + cc] = f2bf(p);
                }
#pragma unroll
                for (int off = 8; off >= 1; off >>= 1)
                    rs += __shfl_xor(rs, off, 16);
                l[reg] += rs;
            }
            asm volatile("s_waitcnt lgkmcnt(0)" ::: "memory");
            __builtin_amdgcn_sched_barrier(0);

            // O += P V
#pragma unroll
            for (int ks = 0; ks < 2; ++ks) {
                const short8 pa = *(const short8*)&Ps[w][cc][ks * 32 + g * 8];
#pragma unroll
                for (int nt = 0; nt < 8; ++nt) {
                    const short8 vf = *(const short8*)&Vs[gg][nt * 16 + cc][ks * 32 + g * 8];
                    o[nt] = __builtin_amdgcn_mfma_f32_16x16x32_bf16(pa, vf, o[nt], 0, 0, 0);
                }
            }
        }
    }

    // merge group 1 into group 0 (Co overlaid on Ks — dead now)
    __syncthreads();
    float* Co = (float*)&Ks[0][0][0];   // [2][16][132]
    if (gg == 1) {
#pragma unroll
        for (int nt = 0; nt < 8; ++nt)
#pragma unroll
            for (int reg = 0; reg < 4; ++reg)
                Co[(wq * 16 + g * 4 + reg) * 132 + nt * 16 + cc] = o[nt][reg];
        if (cc == 0) {
#pragma unroll
            for (int reg = 0; reg < 4; ++reg) {
                Cml[wq][g * 4 + reg][0] = m[reg];
                Cml[wq][g * 4 + reg][1] = l[reg];
            }
        }
    }
    __syncthreads();
    if (gg == 0) {
#pragma unroll
        for (int reg = 0; reg < 4; ++reg) {
            const int r  = g * 4 + reg;
            const float m1 = Cml[wq][r][0];
            const float l1 = Cml[wq][r][1];
            const float M  = fmaxf(m[reg], m1);
            const float e0 = __expf(m[reg] - M);
            const float e1 = __expf(m1 - M);
            const float inv = 1.f / (l[reg] * e0 + l1 * e1);
            const size_t row = (size_t)(b * TLEN + q0 + wq * 16 + r);
#pragma unroll
            for (int nt = 0; nt < 8; ++nt)
                out[row * 128 + nt * 16 + cc] =
                    (o[nt][reg] * e0 + Co[(wq * 16 + r) * 132 + nt * 16 + cc] * e1) * inv;
        }
    }
}

extern "C" void kernel_launch(void* const* d_in, const int* in_sizes, int n_in,
                              void* d_out, int out_size, void* d_ws, size_t ws_size,
                              hipStream_t stream) {
    (void)in_sizes; (void)n_in; (void)out_size; (void)ws_size;
    const float* x = (const float*)d_in[0];      // (8,2048,1024) f32
    const float* W = (const float*)d_in[1];      // (384,1024) f32
    float* out = (float*)d_out;                  // (8,2048,128) f32

    unsigned short* qkbf = (unsigned short*)d_ws;          // [16384][256] bf16
    unsigned short* vtbf = qkbf + (size_t)16384 * 256;     // [8][128][2048] bf16
    unsigned short* wtbf = vtbf + (size_t)8 * 128 * 2048;  // packed W, 768 KB

    pack_w<<<dim3(192), 256, 0, stream>>>(W, wtbf);
    qkv_gemm<<<dim3(256, 3), 256, 0, stream>>>(x, wtbf, qkbf, vtbf);
    attn_fwd<<<dim3(64, 8), 256, 0, stream>>>(qkbf, vtbf, out);
}

// Round 6
// 84.059 us; speedup vs baseline: 1.3431x; 1.3431x over previous
//
#include <hip/hip_runtime.h>
#include <hip/hip_bf16.h>
#include <math.h>

#define D_MODEL 1024
#define TLEN    2048

typedef __attribute__((ext_vector_type(8))) short short8;
typedef __attribute__((ext_vector_type(4))) float f32x4;

static __device__ __forceinline__ unsigned short f2bf(float f) {
    __hip_bfloat16 h = __float2bfloat16(f);
    return __builtin_bit_cast(unsigned short, h);
}

static __device__ __forceinline__ void lds_cp16(void* lds, const void* g) {
    __builtin_amdgcn_global_load_lds(
        (const __attribute__((address_space(1))) unsigned int*)g,
        (__attribute__((address_space(3))) unsigned int*)lds, 16, 0, 0);
}

// ---------------------------------------------------------------------------
// Kernel 0: pack W fp32 [384][1024] -> wt bf16 [np3][kt16][h128][k64],
// swizzled (8-short k-group XOR h&7) for linear gload_lds + swizzled ds_read.
// ---------------------------------------------------------------------------
__global__ __launch_bounds__(256) void pack_w(const float* __restrict__ W,
                                              unsigned short* __restrict__ wt) {
    const int id = blockIdx.x * 256 + threadIdx.x;
    const int h  = id >> 7;
    const int kg = id & 127;
    const int k0 = kg * 8;
    const int kt = k0 >> 6;
    const int kin = k0 & 63;
    const int np = h >> 7;
    const int hp = h & 127;
    const float4 a = *(const float4*)&W[(size_t)h * D_MODEL + k0];
    const float4 b = *(const float4*)&W[(size_t)h * D_MODEL + k0 + 4];
    short8 v;
    v[0] = (short)f2bf(a.x); v[1] = (short)f2bf(a.y);
    v[2] = (short)f2bf(a.z); v[3] = (short)f2bf(a.w);
    v[4] = (short)f2bf(b.x); v[5] = (short)f2bf(b.y);
    v[6] = (short)f2bf(b.z); v[7] = (short)f2bf(b.w);
    const size_t dst = ((size_t)(np * 16 + kt) * 128 + hp) * 64 + (kin ^ ((hp & 7) * 8));
    *(short8*)&wt[dst] = v;
}

// ---------------------------------------------------------------------------
// Kernel 1: qkv = x @ W^T, bf16 MFMA. BM=64, BN=128, BK=64. Grid (256,3).
// Q panel (np==0) pre-scaled by 1/sqrt(128).
// ---------------------------------------------------------------------------
__global__ __launch_bounds__(256, 4) void qkv_gemm(const float* __restrict__ x,
                                                   const unsigned short* __restrict__ wt,
                                                   unsigned short* __restrict__ qk,
                                                   unsigned short* __restrict__ vt) {
    __shared__ unsigned short As[64][88];
    __shared__ unsigned short Bs[128 * 64];

    const int tid  = threadIdx.x;
    const int lane = tid & 63;
    const int w    = tid >> 6;
    const int wm   = w >> 1, wn = w & 1;
    const int cc   = lane & 15, g = lane >> 4;
    const int row0 = blockIdx.x * 64;
    const int np   = blockIdx.y;

    const int xr  = tid >> 2;
    const int xc0 = (tid & 3) * 16;

    const f32x4 zero = {0.f, 0.f, 0.f, 0.f};
    f32x4 acc[2][4];
#pragma unroll
    for (int i = 0; i < 2; ++i)
#pragma unroll
        for (int j = 0; j < 4; ++j) acc[i][j] = zero;

    const float* xrow = x + (size_t)(row0 + xr) * D_MODEL + xc0;
    float4 xa[4];
#pragma unroll
    for (int i = 0; i < 4; ++i) xa[i] = *(const float4*)(xrow + i * 4);

    const unsigned short* wtile0 =
        wt + (size_t)np * 16 * 128 * 64 + (w * 4 * 1024 + lane * 16) / 2;
    unsigned short* bdst = Bs + (w * 4 * 1024) / 2;

    for (int kt = 0; kt < 16; ++kt) {
        __syncthreads();
        {
            short8 s0, s1;
            s0[0] = (short)f2bf(xa[0].x); s0[1] = (short)f2bf(xa[0].y);
            s0[2] = (short)f2bf(xa[0].z); s0[3] = (short)f2bf(xa[0].w);
            s0[4] = (short)f2bf(xa[1].x); s0[5] = (short)f2bf(xa[1].y);
            s0[6] = (short)f2bf(xa[1].z); s0[7] = (short)f2bf(xa[1].w);
            s1[0] = (short)f2bf(xa[2].x); s1[1] = (short)f2bf(xa[2].y);
            s1[2] = (short)f2bf(xa[2].z); s1[3] = (short)f2bf(xa[2].w);
            s1[4] = (short)f2bf(xa[3].x); s1[5] = (short)f2bf(xa[3].y);
            s1[6] = (short)f2bf(xa[3].z); s1[7] = (short)f2bf(xa[3].w);
            *(short8*)&As[xr][xc0]     = s0;
            *(short8*)&As[xr][xc0 + 8] = s1;
        }
        const unsigned short* wtk = wtile0 + (size_t)kt * 128 * 64;
#pragma unroll
        for (int i = 0; i < 4; ++i)
            lds_cp16(bdst + i * 512, wtk + i * 512);
        __syncthreads();

        short8 af[2][2], bf[2][4];
#pragma unroll
        for (int ks = 0; ks < 2; ++ks) {
#pragma unroll
            for (int mt = 0; mt < 2; ++mt)
                af[ks][mt] = *(const short8*)&As[wm * 32 + mt * 16 + cc][ks * 32 + g * 8];
#pragma unroll
            for (int nt = 0; nt < 4; ++nt) {
                const int h = wn * 64 + nt * 16 + cc;
                bf[ks][nt] = *(const short8*)&Bs[h * 64 + (((ks * 4 + g) ^ (h & 7)) << 3)];
            }
        }
        if (kt + 1 < 16) {
#pragma unroll
            for (int i = 0; i < 4; ++i)
                xa[i] = *(const float4*)(xrow + (kt + 1) * 64 + i * 4);
        }
#pragma unroll
        for (int ks = 0; ks < 2; ++ks)
#pragma unroll
            for (int mt = 0; mt < 2; ++mt)
#pragma unroll
                for (int nt = 0; nt < 4; ++nt)
                    acc[mt][nt] = __builtin_amdgcn_mfma_f32_16x16x32_bf16(
                        af[ks][mt], bf[ks][nt], acc[mt][nt], 0, 0, 0);
    }

    const int bb  = row0 >> 11;
    const int tr0 = row0 & 2047;
    const float qs = (np == 0) ? 0.08838834764831845f : 1.0f;
#pragma unroll
    for (int mt = 0; mt < 2; ++mt)
#pragma unroll
        for (int nt = 0; nt < 4; ++nt) {
            const int colp = wn * 64 + nt * 16;
            if (np < 2) {
#pragma unroll
                for (int r = 0; r < 4; ++r) {
                    const int row = row0 + wm * 32 + mt * 16 + g * 4 + r;
                    qk[(size_t)row * 256 + np * 128 + colp + cc] = f2bf(acc[mt][nt][r] * qs);
                }
            } else {
                const int d    = colp + cc;
                const int trow = tr0 + wm * 32 + mt * 16 + g * 4;
                ushort4 u;
                u.x = f2bf(acc[mt][nt][0]);
                u.y = f2bf(acc[mt][nt][1]);
                u.z = f2bf(acc[mt][nt][2]);
                u.w = f2bf(acc[mt][nt][3]);
                *(ushort4*)&vt[((size_t)(bb * 128 + d)) * TLEN + trow] = u;
            }
        }
}

// ---------------------------------------------------------------------------
// Kernel 2: causal flash attention. QBLK=64, grid (32,8)=256 blocks,
// 768 thr = 12 waves: wq=w&3 (16-row q subtile), ggg=w>>2 (KV tile mod 3).
// K/V XOR-swizzled (no pad) -> LDS 125,952 B. 3-way in-block (m,l,o) merge
// via overlay on dead K/V buffers. Defer-max; Q pre-scaled; 1-step prefetch.
// ---------------------------------------------------------------------------
__global__ __launch_bounds__(768, 3) void attn_fwd(const unsigned short* __restrict__ qk,
                                                   const unsigned short* __restrict__ vt,
                                                   float* __restrict__ out) {
    __shared__ unsigned short KV[49152];       // 3x K[64][128] + 3x V[128][64], 98304 B
    __shared__ unsigned short Ps[12][16][72];  // 27648 B

    const int tid  = threadIdx.x;
    const int lane = tid & 63;
    const int w    = tid >> 6;        // 0..11
    const int ggg  = w >> 2;          // KV group 0..2
    const int wq   = w & 3;           // q subtile 0..3
    const int cc   = lane & 15, g = lane >> 4;
    const int qt   = 31 - (int)blockIdx.x;
    const int b    = blockIdx.y;
    const int q0   = qt * 64;

    unsigned short* Ks = KV + ggg * 8192;          // [64][128] swizzled
    unsigned short* Vs = KV + 24576 + ggg * 8192;  // [128][64] swizzled

    // Q A-fragments (pre-scaled), kernel lifetime
    short8 qf[4];
    {
        const unsigned short* qb =
            qk + ((size_t)(b * TLEN + q0 + wq * 16 + cc)) * 256 + g * 8;
#pragma unroll
        for (int kt = 0; kt < 4; ++kt) qf[kt] = *(const short8*)(qb + kt * 32);
    }

    const f32x4 zero = {0.f, 0.f, 0.f, 0.f};
    f32x4 o[8];
#pragma unroll
    for (int nt = 0; nt < 8; ++nt) o[nt] = zero;
    float m[4] = {-INFINITY, -INFINITY, -INFINITY, -INFINITY};
    float l[4] = {0.f, 0.f, 0.f, 0.f};

    const int n      = qt + 1;
    const int nsteps = (n + 2) / 3;

    // staging ids (per 256-thread group): K 64B/thr, V 64B/thr
    const int gl   = tid & 255;
    const int kRow = gl >> 2;          // 0..63
    const int kG0  = (gl & 3) * 4;     // of 16 8-short groups
    const int vRow = gl >> 1;          // 0..127
    const int vG0  = (gl & 1) * 4;     // of 8 8-short groups
    const unsigned short* kgp = qk + ((size_t)(b * TLEN + kRow)) * 256 + 128 + kG0 * 8;
    const unsigned short* vgp = vt + ((size_t)(b * 128 + vRow)) * TLEN + vG0 * 8;

    short8 kr[4], vr[4];
    {
        const int t0 = (ggg < n) ? ggg : (n - 1);
#pragma unroll
        for (int i = 0; i < 4; ++i) kr[i] = *(const short8*)(kgp + (size_t)t0 * 16384 + i * 8);
#pragma unroll
        for (int i = 0; i < 4; ++i) vr[i] = *(const short8*)(vgp + t0 * 64 + i * 8);
    }

    for (int s = 0; s < nsteps; ++s) {
        const int  t      = 3 * s + ggg;
        const bool active = (t < n);
        __syncthreads();   // prior step's frag reads done
#pragma unroll
        for (int i = 0; i < 4; ++i) {
            *(short8*)&Ks[kRow * 128 + (((kG0 + i) ^ (kRow & 7)) << 3)] = kr[i];
            *(short8*)&Vs[vRow * 64  + (((vG0 + i) ^ (vRow & 7)) << 3)] = vr[i];
        }
        __syncthreads();
        if (s + 1 < nsteps) {
            int tn = 3 * (s + 1) + ggg;
            if (tn > n - 1) tn = n - 1;
#pragma unroll
            for (int i = 0; i < 4; ++i) kr[i] = *(const short8*)(kgp + (size_t)tn * 16384 + i * 8);
#pragma unroll
            for (int i = 0; i < 4; ++i) vr[i] = *(const short8*)(vgp + tn * 64 + i * 8);
        }
        if (active) {
            const int j0 = t * 64;
            // S = Q K^T (Q pre-scaled)
            f32x4 sreg[4];
#pragma unroll
            for (int jt = 0; jt < 4; ++jt) sreg[jt] = zero;
#pragma unroll
            for (int kt = 0; kt < 4; ++kt)
#pragma unroll
                for (int jt = 0; jt < 4; ++jt) {
                    const short8 kf = *(const short8*)
                        &Ks[(jt * 16 + cc) * 128 + (((kt * 4 + g) ^ (cc & 7)) << 3)];
                    sreg[jt] = __builtin_amdgcn_mfma_f32_16x16x32_bf16(qf[kt], kf, sreg[jt], 0, 0, 0);
                }

            const bool diag = (t == qt);
            float tmr[4];
#pragma unroll
            for (int reg = 0; reg < 4; ++reg) {
                const int qrow = q0 + wq * 16 + g * 4 + reg;
                float vmax = -INFINITY;
#pragma unroll
                for (int jt = 0; jt < 4; ++jt) {
                    float v = sreg[jt][reg];
                    if (diag && (j0 + jt * 16 + cc) > qrow) v = -INFINITY;
                    sreg[jt][reg] = v;
                    vmax = fmaxf(vmax, v);
                }
#pragma unroll
                for (int off = 8; off >= 1; off >>= 1)
                    vmax = fmaxf(vmax, __shfl_xor(vmax, off, 16));
                tmr[reg] = vmax;
            }
            const bool small = (tmr[0] <= m[0] + 8.f) && (tmr[1] <= m[1] + 8.f) &&
                               (tmr[2] <= m[2] + 8.f) && (tmr[3] <= m[3] + 8.f);
            if (!__all(small)) {
#pragma unroll
                for (int reg = 0; reg < 4; ++reg) {
                    const float newm  = fmaxf(m[reg], tmr[reg]);
                    const float alpha = __expf(m[reg] - newm);
                    m[reg] = newm;
                    l[reg] *= alpha;
#pragma unroll
                    for (int nt = 0; nt < 8; ++nt) o[nt][reg] *= alpha;
                }
            }
#pragma unroll
            for (int reg = 0; reg < 4; ++reg) {
                float rs = 0.f;
#pragma unroll
                for (int jt = 0; jt < 4; ++jt) {
                    const float p = __expf(sreg[jt][reg] - m[reg]);
                    rs += p;
                    Ps[w][g * 4 + reg][jt * 16 + cc] = f2bf(p);
                }
#pragma unroll
                for (int off = 8; off >= 1; off >>= 1)
                    rs += __shfl_xor(rs, off, 16);
                l[reg] += rs;
            }
            asm volatile("s_waitcnt lgkmcnt(0)" ::: "memory");
            __builtin_amdgcn_sched_barrier(0);

            // O += P V
#pragma unroll
            for (int ks = 0; ks < 2; ++ks) {
                const short8 pa = *(const short8*)&Ps[w][cc][ks * 32 + g * 8];
#pragma unroll
                for (int nt = 0; nt < 8; ++nt) {
                    const short8 vf = *(const short8*)
                        &Vs[(nt * 16 + cc) * 64 + (((ks * 4 + g) ^ (cc & 7)) << 3)];
                    o[nt] = __builtin_amdgcn_mfma_f32_16x16x32_bf16(pa, vf, o[nt], 0, 0, 0);
                }
            }
        }
    }

    // 3-way merge: groups 1,2 park partials in overlays (K/V, Ps dead)
    __syncthreads();
    float* Co  = (float*)KV;            // 2 x [64][128] f32 = 65536 B
    float* Cml = (float*)&Ps[0][0][0];  // 2 x 64 x 2 f32
    if (ggg != 0) {
        float* co = Co + (size_t)(ggg - 1) * 8192;
#pragma unroll
        for (int nt = 0; nt < 8; ++nt)
#pragma unroll
            for (int reg = 0; reg < 4; ++reg)
                co[(wq * 16 + g * 4 + reg) * 128 + nt * 16 + cc] = o[nt][reg];
        if (cc == 0) {
#pragma unroll
            for (int reg = 0; reg < 4; ++reg) {
                const int rl = wq * 16 + g * 4 + reg;
                Cml[((ggg - 1) * 64 + rl) * 2 + 0] = m[reg];
                Cml[((ggg - 1) * 64 + rl) * 2 + 1] = l[reg];
            }
        }
    }
    __syncthreads();
    if (ggg == 0) {
#pragma unroll
        for (int reg = 0; reg < 4; ++reg) {
            const int rl = wq * 16 + g * 4 + reg;
            const float m1 = Cml[rl * 2], l1v = Cml[rl * 2 + 1];
            const float m2 = Cml[(64 + rl) * 2], l2v = Cml[(64 + rl) * 2 + 1];
            const float M  = fmaxf(fmaxf(m[reg], m1), m2);
            const float e0 = __expf(m[reg] - M);
            const float e1 = __expf(m1 - M);
            const float e2 = __expf(m2 - M);
            const float inv = 1.f / (l[reg] * e0 + l1v * e1 + l2v * e2);
            const size_t row = (size_t)(b * TLEN + q0 + rl);
#pragma unroll
            for (int nt = 0; nt < 8; ++nt)
                out[row * 128 + nt * 16 + cc] =
                    (o[nt][reg] * e0 +
                     Co[rl * 128 + nt * 16 + cc] * e1 +
                     Co[8192 + rl * 128 + nt * 16 + cc] * e2) * inv;
        }
    }
}

extern "C" void kernel_launch(void* const* d_in, const int* in_sizes, int n_in,
                              void* d_out, int out_size, void* d_ws, size_t ws_size,
                              hipStream_t stream) {
    (void)in_sizes; (void)n_in; (void)out_size; (void)ws_size;
    const float* x = (const float*)d_in[0];      // (8,2048,1024) f32
    const float* W = (const float*)d_in[1];      // (384,1024) f32
    float* out = (float*)d_out;                  // (8,2048,128) f32

    unsigned short* qkbf = (unsigned short*)d_ws;          // [16384][256] bf16
    unsigned short* vtbf = qkbf + (size_t)16384 * 256;     // [8][128][2048] bf16
    unsigned short* wtbf = vtbf + (size_t)8 * 128 * 2048;  // packed W, 768 KB

    pack_w<<<dim3(192), 256, 0, stream>>>(W, wtbf);
    qkv_gemm<<<dim3(256, 3), 256, 0, stream>>>(x, wtbf, qkbf, vtbf);
    attn_fwd<<<dim3(32, 8), 768, 0, stream>>>(qkbf, vtbf, out);
}

// Round 7
// 68.903 us; speedup vs baseline: 1.6385x; 1.2200x over previous
//
#include <hip/hip_runtime.h>
#include <hip/hip_bf16.h>
#include <math.h>

#define D_MODEL 1024
#define TLEN    2048

typedef __attribute__((ext_vector_type(8))) short short8;
typedef __attribute__((ext_vector_type(4))) float f32x4;

static __device__ __forceinline__ unsigned short f2bf(float f) {
    __hip_bfloat16 h = __float2bfloat16(f);
    return __builtin_bit_cast(unsigned short, h);
}
static __device__ __forceinline__ float bf2f(unsigned short u) {
    unsigned int x = ((unsigned int)u) << 16;
    return __builtin_bit_cast(float, x);
}
static __device__ __forceinline__ void lds_cp16(void* lds, const void* g) {
    __builtin_amdgcn_global_load_lds(
        (const __attribute__((address_space(1))) unsigned int*)g,
        (__attribute__((address_space(3))) unsigned int*)lds, 16, 0, 0);
}

// ---------------------------------------------------------------------------
// Kernel 0: pack W fp32 [384][1024] -> wt bf16 [np3][kt16][h128][k64],
// swizzled (8-short k-group XOR h&7).
// ---------------------------------------------------------------------------
__global__ __launch_bounds__(256) void pack_w(const float* __restrict__ W,
                                              unsigned short* __restrict__ wt) {
    const int id = blockIdx.x * 256 + threadIdx.x;
    const int h  = id >> 7;
    const int kg = id & 127;
    const int k0 = kg * 8;
    const int kt = k0 >> 6;
    const int kin = k0 & 63;
    const int np = h >> 7;
    const int hp = h & 127;
    const float4 a = *(const float4*)&W[(size_t)h * D_MODEL + k0];
    const float4 b = *(const float4*)&W[(size_t)h * D_MODEL + k0 + 4];
    short8 v;
    v[0] = (short)f2bf(a.x); v[1] = (short)f2bf(a.y);
    v[2] = (short)f2bf(a.z); v[3] = (short)f2bf(a.w);
    v[4] = (short)f2bf(b.x); v[5] = (short)f2bf(b.y);
    v[6] = (short)f2bf(b.z); v[7] = (short)f2bf(b.w);
    const size_t dst = ((size_t)(np * 16 + kt) * 128 + hp) * 64 + (kin ^ ((hp & 7) * 8));
    *(short8*)&wt[dst] = v;
}

// ---------------------------------------------------------------------------
// Kernel 1: qkv = x @ W^T, bf16 MFMA (unchanged). Q panel pre-scaled.
// ---------------------------------------------------------------------------
__global__ __launch_bounds__(256, 4) void qkv_gemm(const float* __restrict__ x,
                                                   const unsigned short* __restrict__ wt,
                                                   unsigned short* __restrict__ qk,
                                                   unsigned short* __restrict__ vt) {
    __shared__ unsigned short As[64][88];
    __shared__ unsigned short Bs[128 * 64];

    const int tid  = threadIdx.x;
    const int lane = tid & 63;
    const int w    = tid >> 6;
    const int wm   = w >> 1, wn = w & 1;
    const int cc   = lane & 15, g = lane >> 4;
    const int row0 = blockIdx.x * 64;
    const int np   = blockIdx.y;

    const int xr  = tid >> 2;
    const int xc0 = (tid & 3) * 16;

    const f32x4 zero = {0.f, 0.f, 0.f, 0.f};
    f32x4 acc[2][4];
#pragma unroll
    for (int i = 0; i < 2; ++i)
#pragma unroll
        for (int j = 0; j < 4; ++j) acc[i][j] = zero;

    const float* xrow = x + (size_t)(row0 + xr) * D_MODEL + xc0;
    float4 xa[4];
#pragma unroll
    for (int i = 0; i < 4; ++i) xa[i] = *(const float4*)(xrow + i * 4);

    const unsigned short* wtile0 =
        wt + (size_t)np * 16 * 128 * 64 + (w * 4 * 1024 + lane * 16) / 2;
    unsigned short* bdst = Bs + (w * 4 * 1024) / 2;

    for (int kt = 0; kt < 16; ++kt) {
        __syncthreads();
        {
            short8 s0, s1;
            s0[0] = (short)f2bf(xa[0].x); s0[1] = (short)f2bf(xa[0].y);
            s0[2] = (short)f2bf(xa[0].z); s0[3] = (short)f2bf(xa[0].w);
            s0[4] = (short)f2bf(xa[1].x); s0[5] = (short)f2bf(xa[1].y);
            s0[6] = (short)f2bf(xa[1].z); s0[7] = (short)f2bf(xa[1].w);
            s1[0] = (short)f2bf(xa[2].x); s1[1] = (short)f2bf(xa[2].y);
            s1[2] = (short)f2bf(xa[2].z); s1[3] = (short)f2bf(xa[2].w);
            s1[4] = (short)f2bf(xa[3].x); s1[5] = (short)f2bf(xa[3].y);
            s1[6] = (short)f2bf(xa[3].z); s1[7] = (short)f2bf(xa[3].w);
            *(short8*)&As[xr][xc0]     = s0;
            *(short8*)&As[xr][xc0 + 8] = s1;
        }
        const unsigned short* wtk = wtile0 + (size_t)kt * 128 * 64;
#pragma unroll
        for (int i = 0; i < 4; ++i)
            lds_cp16(bdst + i * 512, wtk + i * 512);
        __syncthreads();

        short8 af[2][2], bf[2][4];
#pragma unroll
        for (int ks = 0; ks < 2; ++ks) {
#pragma unroll
            for (int mt = 0; mt < 2; ++mt)
                af[ks][mt] = *(const short8*)&As[wm * 32 + mt * 16 + cc][ks * 32 + g * 8];
#pragma unroll
            for (int nt = 0; nt < 4; ++nt) {
                const int h = wn * 64 + nt * 16 + cc;
                bf[ks][nt] = *(const short8*)&Bs[h * 64 + (((ks * 4 + g) ^ (h & 7)) << 3)];
            }
        }
        if (kt + 1 < 16) {
#pragma unroll
            for (int i = 0; i < 4; ++i)
                xa[i] = *(const float4*)(xrow + (kt + 1) * 64 + i * 4);
        }
#pragma unroll
        for (int ks = 0; ks < 2; ++ks)
#pragma unroll
            for (int mt = 0; mt < 2; ++mt)
#pragma unroll
                for (int nt = 0; nt < 4; ++nt)
                    acc[mt][nt] = __builtin_amdgcn_mfma_f32_16x16x32_bf16(
                        af[ks][mt], bf[ks][nt], acc[mt][nt], 0, 0, 0);
    }

    const int bb  = row0 >> 11;
    const int tr0 = row0 & 2047;
    const float qs = (np == 0) ? 0.08838834764831845f : 1.0f;
#pragma unroll
    for (int mt = 0; mt < 2; ++mt)
#pragma unroll
        for (int nt = 0; nt < 4; ++nt) {
            const int colp = wn * 64 + nt * 16;
            if (np < 2) {
#pragma unroll
                for (int r = 0; r < 4; ++r) {
                    const int row = row0 + wm * 32 + mt * 16 + g * 4 + r;
                    qk[(size_t)row * 256 + np * 128 + colp + cc] = f2bf(acc[mt][nt][r] * qs);
                }
            } else {
                const int d    = colp + cc;
                const int trow = tr0 + wm * 32 + mt * 16 + g * 4;
                ushort4 u;
                u.x = f2bf(acc[mt][nt][0]);
                u.y = f2bf(acc[mt][nt][1]);
                u.z = f2bf(acc[mt][nt][2]);
                u.w = f2bf(acc[mt][nt][3]);
                *(ushort4*)&vt[((size_t)(bb * 128 + d)) * TLEN + trow] = u;
            }
        }
}

// ---------------------------------------------------------------------------
// Kernel 2: attention partial. Block = (qt, ggg, b): 256 thr = 4 waves, each
// wave one 16-row q-subtile; block handles KV tiles t = ggg mod 3.
// Swapped QK^T (S^T in regs) -> in-lane softmax (2 shfl_xor per reduction).
// Writes un-normalized o (bf16) + (m,l) partials; merge kernel combines.
// ---------------------------------------------------------------------------
__global__ __launch_bounds__(256, 3) void attn_part(const unsigned short* __restrict__ qk,
                                                    const unsigned short* __restrict__ vt,
                                                    unsigned short* __restrict__ po,
                                                    float2* __restrict__ ml) {
    __shared__ unsigned short Ks[64 * 128];    // swizzled
    __shared__ unsigned short Vs[128 * 64];    // swizzled
    __shared__ unsigned short Ps[4][16][72];

    const int tid  = threadIdx.x;
    const int lane = tid & 63;
    const int w    = tid >> 6;       // q subtile 0..3
    const int cc   = lane & 15, g = lane >> 4;
    const int bx   = blockIdx.x;     // 0..95
    const int qt   = 31 - (bx / 3);  // long blocks first
    const int ggg  = bx % 3;
    const int b    = blockIdx.y;
    const int q0   = qt * 64;
    const int slot = (b * 32 + qt) * 3 + ggg;
    const int n    = qt + 1;
    const int cnt  = (n > ggg) ? ((n - ggg + 2) / 3) : 0;

    if (cnt == 0) {    // no tiles for this group (qt==0, ggg>0)
#pragma unroll
        for (int nt = 0; nt < 8; ++nt)
#pragma unroll
            for (int r = 0; r < 4; ++r)
                po[((size_t)slot * 64 + w * 16 + g * 4 + r) * 128 + nt * 16 + cc] = 0;
        if (g == 0) ml[slot * 64 + w * 16 + cc] = make_float2(-INFINITY, 0.f);
        return;
    }

    // Q B-fragments (pre-scaled in gemm), kernel lifetime
    short8 qf[4];
    {
        const unsigned short* qb =
            qk + ((size_t)(b * TLEN + q0 + w * 16 + cc)) * 256 + g * 8;
#pragma unroll
        for (int kt = 0; kt < 4; ++kt) qf[kt] = *(const short8*)(qb + kt * 32);
    }

    const f32x4 zero = {0.f, 0.f, 0.f, 0.f};
    f32x4 o[8];
#pragma unroll
    for (int nt = 0; nt < 8; ++nt) o[nt] = zero;
    float mrun = -INFINITY, lrun = 0.f;

    // hoisted swizzled LDS read offsets (shorts)
    int koff[4], voff[2];
#pragma unroll
    for (int kt = 0; kt < 4; ++kt)
        koff[kt] = cc * 128 + (((kt * 4 + g) ^ (cc & 7)) << 3);
#pragma unroll
    for (int ks = 0; ks < 2; ++ks)
        voff[ks] = cc * 64 + (((ks * 4 + g) ^ (cc & 7)) << 3);

    // staging ids: K 64B/thr (4 rows/thr grp), V 64B/thr
    const int kRow = tid >> 2;
    const int kG0  = (tid & 3) * 4;
    const int vRow = tid >> 1;
    const int vG0  = (tid & 1) * 4;
    const unsigned short* kgp = qk + ((size_t)(b * TLEN + kRow)) * 256 + 128 + kG0 * 8;
    const unsigned short* vgp = vt + ((size_t)(b * 128 + vRow)) * TLEN + vG0 * 8;

    short8 kr[4], vr[4];
#pragma unroll
    for (int i = 0; i < 4; ++i) kr[i] = *(const short8*)(kgp + (size_t)ggg * 16384 + i * 8);
#pragma unroll
    for (int i = 0; i < 4; ++i) vr[i] = *(const short8*)(vgp + ggg * 64 + i * 8);

    for (int s = 0; s < cnt; ++s) {
        const int t  = 3 * s + ggg;
        const int j0 = t * 64;
        __syncthreads();    // prior step's LDS reads done (4 waves only)
#pragma unroll
        for (int i = 0; i < 4; ++i) {
            *(short8*)&Ks[kRow * 128 + (((kG0 + i) ^ (kRow & 7)) << 3)] = kr[i];
            *(short8*)&Vs[vRow * 64  + (((vG0 + i) ^ (vRow & 7)) << 3)] = vr[i];
        }
        __syncthreads();
        if (s + 1 < cnt) {
            const int tn = t + 3;
#pragma unroll
            for (int i = 0; i < 4; ++i) kr[i] = *(const short8*)(kgp + (size_t)tn * 16384 + i * 8);
#pragma unroll
            for (int i = 0; i < 4; ++i) vr[i] = *(const short8*)(vgp + tn * 64 + i * 8);
        }

        // S^T = K Q^T : lane (g,cc) holds S[q=q0+w*16+cc][j=j0+16jt+4g+r]
        f32x4 st[4];
#pragma unroll
        for (int jt = 0; jt < 4; ++jt) st[jt] = zero;
        __builtin_amdgcn_s_setprio(1);
#pragma unroll
        for (int kt = 0; kt < 4; ++kt)
#pragma unroll
            for (int jt = 0; jt < 4; ++jt) {
                const short8 kf = *(const short8*)&Ks[koff[kt] + jt * 2048];
                st[jt] = __builtin_amdgcn_mfma_f32_16x16x32_bf16(kf, qf[kt], st[jt], 0, 0, 0);
            }
        __builtin_amdgcn_s_setprio(0);

        if (t == qt) {   // diagonal tile: causal mask
            const int qg = q0 + w * 16 + cc;
            const int jb = j0 + 4 * g;
#pragma unroll
            for (int jt = 0; jt < 4; ++jt)
#pragma unroll
                for (int r = 0; r < 4; ++r)
                    if (jb + jt * 16 + r > qg) st[jt][r] = -INFINITY;
        }
        float pmax = -INFINITY;
#pragma unroll
        for (int jt = 0; jt < 4; ++jt) {
            const float a = fmaxf(st[jt][0], st[jt][1]);
            const float c = fmaxf(st[jt][2], st[jt][3]);
            pmax = fmaxf(pmax, fmaxf(a, c));
        }
        pmax = fmaxf(pmax, __shfl_xor(pmax, 16));
        pmax = fmaxf(pmax, __shfl_xor(pmax, 32));

        // defer-max: only rescale when some row grew by > 8
        if (!__all(pmax <= mrun + 8.f)) {
            const float newm  = fmaxf(mrun, pmax);
            const float alpha = __expf(mrun - newm);
            mrun = newm;
            lrun *= alpha;
            float arow[4];
#pragma unroll
            for (int r = 0; r < 4; ++r) arow[r] = __shfl(alpha, 20 * g + r);
#pragma unroll
            for (int nt = 0; nt < 8; ++nt)
#pragma unroll
                for (int r = 0; r < 4; ++r) o[nt][r] *= arow[r];
        }

        float rs = 0.f;
#pragma unroll
        for (int jt = 0; jt < 4; ++jt) {
            const float p0 = __expf(st[jt][0] - mrun);
            const float p1 = __expf(st[jt][1] - mrun);
            const float p2 = __expf(st[jt][2] - mrun);
            const float p3 = __expf(st[jt][3] - mrun);
            rs += (p0 + p1) + (p2 + p3);
            uint2 pw;
            pw.x = (unsigned int)f2bf(p0) | ((unsigned int)f2bf(p1) << 16);
            pw.y = (unsigned int)f2bf(p2) | ((unsigned int)f2bf(p3) << 16);
            *(uint2*)&Ps[w][cc][jt * 16 + 4 * g] = pw;
        }
        rs += __shfl_xor(rs, 16);
        rs += __shfl_xor(rs, 32);
        lrun += rs;

        asm volatile("s_waitcnt lgkmcnt(0)" ::: "memory");
        __builtin_amdgcn_sched_barrier(0);

        // O += P V
        __builtin_amdgcn_s_setprio(1);
#pragma unroll
        for (int ks = 0; ks < 2; ++ks) {
            const short8 pa = *(const short8*)&Ps[w][cc][ks * 32 + g * 8];
#pragma unroll
            for (int nt = 0; nt < 8; ++nt) {
                const short8 vf = *(const short8*)&Vs[voff[ks] + nt * 1024];
                o[nt] = __builtin_amdgcn_mfma_f32_16x16x32_bf16(pa, vf, o[nt], 0, 0, 0);
            }
        }
        __builtin_amdgcn_s_setprio(0);
    }

    // write partial (un-normalized o bf16; m,l f32)
#pragma unroll
    for (int nt = 0; nt < 8; ++nt)
#pragma unroll
        for (int r = 0; r < 4; ++r)
            po[((size_t)slot * 64 + w * 16 + g * 4 + r) * 128 + nt * 16 + cc] =
                f2bf(o[nt][r]);
    if (g == 0) ml[slot * 64 + w * 16 + cc] = make_float2(mrun, lrun);
}

// ---------------------------------------------------------------------------
// Kernel 3: merge the 3 partials per q-row, normalize, write f32 out.
// Grid 256 blocks (b*32+qt), 256 thr: thread = (row 0..63, 32-col segment).
// ---------------------------------------------------------------------------
__global__ __launch_bounds__(256) void attn_merge(const unsigned short* __restrict__ po,
                                                  const float2* __restrict__ ml,
                                                  float* __restrict__ out) {
    const int bq   = blockIdx.x;
    const int row  = threadIdx.x >> 2;
    const int cs   = (threadIdx.x & 3) * 32;
    const int slot = bq * 3;

    const float2 ml0 = ml[(size_t)(slot + 0) * 64 + row];
    const float2 ml1 = ml[(size_t)(slot + 1) * 64 + row];
    const float2 ml2 = ml[(size_t)(slot + 2) * 64 + row];
    const float M  = fmaxf(fmaxf(ml0.x, ml1.x), ml2.x);
    float e0 = __expf(ml0.x - M);
    float e1 = __expf(ml1.x - M);
    float e2 = __expf(ml2.x - M);
    const float inv = 1.f / (ml0.y * e0 + ml1.y * e1 + ml2.y * e2);
    e0 *= inv; e1 *= inv; e2 *= inv;

    const unsigned short* p0 = po + ((size_t)(slot + 0) * 64 + row) * 128 + cs;
    const unsigned short* p1 = po + ((size_t)(slot + 1) * 64 + row) * 128 + cs;
    const unsigned short* p2 = po + ((size_t)(slot + 2) * 64 + row) * 128 + cs;
    float* op = out + ((size_t)bq * 64 + row) * 128 + cs;

#pragma unroll
    for (int i = 0; i < 4; ++i) {
        const short8 a = *(const short8*)(p0 + i * 8);
        const short8 b = *(const short8*)(p1 + i * 8);
        const short8 c = *(const short8*)(p2 + i * 8);
        float4 o0, o1;
        o0.x = bf2f((unsigned short)a[0]) * e0 + bf2f((unsigned short)b[0]) * e1 + bf2f((unsigned short)c[0]) * e2;
        o0.y = bf2f((unsigned short)a[1]) * e0 + bf2f((unsigned short)b[1]) * e1 + bf2f((unsigned short)c[1]) * e2;
        o0.z = bf2f((unsigned short)a[2]) * e0 + bf2f((unsigned short)b[2]) * e1 + bf2f((unsigned short)c[2]) * e2;
        o0.w = bf2f((unsigned short)a[3]) * e0 + bf2f((unsigned short)b[3]) * e1 + bf2f((unsigned short)c[3]) * e2;
        o1.x = bf2f((unsigned short)a[4]) * e0 + bf2f((unsigned short)b[4]) * e1 + bf2f((unsigned short)c[4]) * e2;
        o1.y = bf2f((unsigned short)a[5]) * e0 + bf2f((unsigned short)b[5]) * e1 + bf2f((unsigned short)c[5]) * e2;
        o1.z = bf2f((unsigned short)a[6]) * e0 + bf2f((unsigned short)b[6]) * e1 + bf2f((unsigned short)c[6]) * e2;
        o1.w = bf2f((unsigned short)a[7]) * e0 + bf2f((unsigned short)b[7]) * e1 + bf2f((unsigned short)c[7]) * e2;
        *(float4*)(op + i * 8)     = o0;
        *(float4*)(op + i * 8 + 4) = o1;
    }
}

extern "C" void kernel_launch(void* const* d_in, const int* in_sizes, int n_in,
                              void* d_out, int out_size, void* d_ws, size_t ws_size,
                              hipStream_t stream) {
    (void)in_sizes; (void)n_in; (void)out_size; (void)ws_size;
    const float* x = (const float*)d_in[0];      // (8,2048,1024) f32
    const float* W = (const float*)d_in[1];      // (384,1024) f32
    float* out = (float*)d_out;                  // (8,2048,128) f32

    unsigned short* qkbf = (unsigned short*)d_ws;           // [16384][256] bf16
    unsigned short* vtbf = qkbf + (size_t)16384 * 256;      // [8][128][2048] bf16
    unsigned short* wtbf = vtbf + (size_t)8 * 128 * 2048;   // packed W, 768 KB
    unsigned short* pobf = wtbf + (size_t)3 * 16 * 128 * 64;        // partials o
    float2*         mlf  = (float2*)(pobf + (size_t)768 * 64 * 128); // partials m,l

    pack_w<<<dim3(192), 256, 0, stream>>>(W, wtbf);
    qkv_gemm<<<dim3(256, 3), 256, 0, stream>>>(x, wtbf, qkbf, vtbf);
    attn_part<<<dim3(96, 8), 256, 0, stream>>>(qkbf, vtbf, pobf, mlf);
    attn_merge<<<dim3(256), 256, 0, stream>>>(pobf, mlf, out);
}